// Round 2
// baseline (231.199 us; speedup 1.0000x reference)
//
#include <hip/hip_runtime.h>
#include <hip/hip_bf16.h>

#define NBATCH 16384
#define WPB 4          // waves (samples) per block
#define BLOCK 256

__device__ __forceinline__ float clamp01(float x){ return fminf(fmaxf(x, 0.f), 1.f); }

__global__ __launch_bounds__(BLOCK, 4) void nnue_fwd_f32(
    const int* __restrict__ wi, const int* __restrict__ bi,
    const float* __restrict__ stm,
    const float* __restrict__ ftw, const float* __restrict__ ftb,
    const float* __restrict__ l1w, const float* __restrict__ l1b,
    const float* __restrict__ l2w, const float* __restrict__ l2b,
    const float* __restrict__ l3w, const float* __restrict__ l3b,
    float* __restrict__ out)
{
    __shared__ __align__(16) float l1w_s[16*512];   // 32 KB: half of l1_w per pass
    __shared__ float l2w_s[32*33];                  // +1 pad rows
    __shared__ float l1b_s[32], l2b_s[32], l3w_s[32];
    __shared__ int idx_s[WPB][64];

    const int tid  = threadIdx.x;
    const int lane = tid & 63;
    const int wv   = tid >> 6;
    const int s    = blockIdx.x * WPB + wv;        // sample id

    // ---- stage small weights + l1 pass-1 (rows 0..15) ----
    {
        const float4* src = (const float4*)l1w;    // 16384 floats = 4096 float4
        float4* dst = (float4*)l1w_s;              // 2048 float4 per pass
        #pragma unroll
        for (int i = 0; i < 8; ++i) dst[tid + i*BLOCK] = src[tid + i*BLOCK];
    }
    for (int i = tid; i < 1024; i += BLOCK)
        l2w_s[(i >> 5)*33 + (i & 31)] = l2w[i];
    if (tid < 32) {
        l1b_s[tid] = l1b[tid];
        l2b_s[tid] = l2b[tid];
        l3w_s[tid] = l3w[tid];
    }
    {   // lanes 0-31: white idx, lanes 32-63: black idx
        int bse = s*32 + (lane & 31);
        idx_s[wv][lane] = (lane < 32) ? wi[bse] : bi[bse];
    }
    __syncthreads();

    const int chunk = lane & 31;   // this lane's dims: chunk*8 .. chunk*8+7
    const int hsel  = lane & 32;   // 0 = white half-wave, 32 = black

    // ---- embedding bag: init with ft_b, accumulate 32 rows (f32) ----
    float acc[8];
    {
        float4 a = *(const float4*)(ftb + chunk*8);
        float4 b = *(const float4*)(ftb + chunk*8 + 4);
        acc[0]=a.x; acc[1]=a.y; acc[2]=a.z; acc[3]=a.w;
        acc[4]=b.x; acc[5]=b.y; acc[6]=b.z; acc[7]=b.w;
    }
    #pragma unroll 8
    for (int j = 0; j < 32; ++j) {
        int row = idx_s[wv][j + hsel];             // 2-addr broadcast, free
        const float* rp = ftw + (size_t)row*256 + chunk*8;
        float4 a = *(const float4*)rp;
        float4 b = *(const float4*)(rp + 4);
        acc[0]+=a.x; acc[1]+=a.y; acc[2]+=a.z; acc[3]+=a.w;
        acc[4]+=b.x; acc[5]+=b.y; acc[6]+=b.z; acc[7]+=b.w;
    }
    #pragma unroll
    for (int k = 0; k < 8; ++k) acc[k] = clamp01(acc[k]);

    // ---- stm swap: lane ends up holding hidden[lane*8 .. lane*8+7] ----
    const bool wf = stm[s] > 0.5f;
    float h[8];
    #pragma unroll
    for (int k = 0; k < 8; ++k) {
        float x = __shfl_xor(acc[k], 32, 64);
        h[k] = wf ? acc[k] : x;
    }

    // ---- l1 pass 1: outputs 0..15 ----
    float p[32];
    #pragma unroll
    for (int o = 0; o < 16; ++o) {
        float4 wa = *(const float4*)&l1w_s[o*512 + lane*8];
        float4 wb = *(const float4*)&l1w_s[o*512 + lane*8 + 4];
        p[o] = h[0]*wa.x + h[1]*wa.y + h[2]*wa.z + h[3]*wa.w
             + h[4]*wb.x + h[5]*wb.y + h[6]*wb.z + h[7]*wb.w;
    }
    __syncthreads();   // all waves done reading pass-1 weights

    // ---- stage l1 pass-2 (rows 16..31) ----
    {
        const float4* src = (const float4*)l1w;
        float4* dst = (float4*)l1w_s;
        #pragma unroll
        for (int i = 0; i < 8; ++i) dst[tid + i*BLOCK] = src[2048 + tid + i*BLOCK];
    }
    __syncthreads();

    #pragma unroll
    for (int o = 0; o < 16; ++o) {
        float4 wa = *(const float4*)&l1w_s[o*512 + lane*8];
        float4 wb = *(const float4*)&l1w_s[o*512 + lane*8 + 4];
        p[16+o] = h[0]*wa.x + h[1]*wa.y + h[2]*wa.z + h[3]*wa.w
                + h[4]*wb.x + h[5]*wb.y + h[6]*wb.z + h[7]*wb.w;
    }

    // ---- full 64-lane butterfly: every lane gets all 32 sums ----
    #pragma unroll
    for (int o = 0; o < 32; ++o) {
        #pragma unroll
        for (int d = 1; d < 64; d <<= 1)
            p[o] += __shfl_xor(p[o], d, 64);
    }
    float x1[32];
    #pragma unroll
    for (int o = 0; o < 32; ++o) x1[o] = clamp01(p[o] + l1b_s[o]);

    // ---- l2: lane j (dup at j+32) owns output j ----
    const int j2 = lane & 31;
    float a2 = l2b_s[j2];
    #pragma unroll
    for (int i = 0; i < 32; ++i) a2 += x1[i] * l2w_s[j2*33 + i];
    float x2 = clamp01(a2);

    // ---- l3: reduce 32 outputs within each half-wave ----
    float r = x2 * l3w_s[j2];
    #pragma unroll
    for (int d = 16; d >= 1; d >>= 1) r += __shfl_xor(r, d, 64);

    if (lane == 0) out[s] = r + l3b[0];
}

extern "C" void kernel_launch(void* const* d_in, const int* in_sizes, int n_in,
                              void* d_out, int out_size, void* d_ws, size_t ws_size,
                              hipStream_t stream)
{
    const int*   wi  = (const int*)d_in[0];
    const int*   bi  = (const int*)d_in[2];
    const float* stm = (const float*)d_in[4];
    const float* ftw = (const float*)d_in[5];
    const float* ftb = (const float*)d_in[6];
    const float* l1w = (const float*)d_in[7];
    const float* l1b = (const float*)d_in[8];
    const float* l2w = (const float*)d_in[9];
    const float* l2b = (const float*)d_in[10];
    const float* l3w = (const float*)d_in[11];
    const float* l3b = (const float*)d_in[12];
    nnue_fwd_f32<<<dim3(NBATCH/WPB), dim3(BLOCK), 0, stream>>>(
        wi, bi, stm, ftw, ftb, l1w, l1b, l2w, l2b, l3w, l3b,
        (float*)d_out);
}